// Round 1
// baseline (243.268 us; speedup 1.0000x reference)
//
#include <hip/hip_runtime.h>
#include <hip/hip_bf16.h>
#include <stdint.h>
#include <math.h>

#define SEQ 2048
#define DM 1024
#define NH 16
#define DK 64

typedef __attribute__((ext_vector_type(8))) short short8;
typedef __attribute__((ext_vector_type(4))) short short4v;
typedef __attribute__((ext_vector_type(4))) float f32x4;

__device__ __forceinline__ float bf2f(unsigned short s) {
  unsigned u = ((unsigned)s) << 16; float f; __builtin_memcpy(&f, &u, 4); return f;
}
__device__ __forceinline__ unsigned short f2bf(float f) {
  unsigned u; __builtin_memcpy(&u, &f, 4);
  u += 0x7FFFu + ((u >> 16) & 1u);          // RNE
  return (unsigned short)(u >> 16);
}
__device__ __forceinline__ f32x4 mfma16(short8 a, short8 b, f32x4 c) {
  return __builtin_amdgcn_mfma_f32_16x16x32_bf16(a, b, c, 0, 0, 0);
}
__device__ __forceinline__ void gload_lds16(const void* g, void* l) {
  __builtin_amdgcn_global_load_lds((const __attribute__((address_space(1))) void*)g,
                                   (__attribute__((address_space(3))) void*)l, 16, 0, 0);
}

// ---------------- prep: fp32 -> bf16 for x and the 4 weight matrices ----------------
__global__ __launch_bounds__(256) void prep_kernel(
    const float* __restrict__ x, const float* __restrict__ Wq,
    const float* __restrict__ Wk, const float* __restrict__ Wv,
    const float* __restrict__ Wo, __hip_bfloat16* __restrict__ xb,
    __hip_bfloat16* __restrict__ Wb) {
  int chunk = blockIdx.x * 256 + threadIdx.x;   // 1,048,576 chunks of 8 elems
  const float* src; __hip_bfloat16* dst;
  if (chunk < 524288) { src = x + (size_t)chunk * 8; dst = xb + (size_t)chunk * 8; }
  else {
    int wc = chunk - 524288; int wi = wc >> 17; int wo_ = wc & 131071;
    const float* Ws = (wi == 0) ? Wq : (wi == 1) ? Wk : (wi == 2) ? Wv : Wo;
    src = Ws + (size_t)wo_ * 8; dst = Wb + (size_t)wi * 1048576 + (size_t)wo_ * 8;
  }
  float4 a = *(const float4*)src; float4 b = *(const float4*)(src + 4);
  union { short8 v; unsigned short e[8]; } u;
  u.e[0] = f2bf(a.x); u.e[1] = f2bf(a.y); u.e[2] = f2bf(a.z); u.e[3] = f2bf(a.w);
  u.e[4] = f2bf(b.x); u.e[5] = f2bf(b.y); u.e[6] = f2bf(b.z); u.e[7] = f2bf(b.w);
  *(short8*)dst = u.v;
}

// ---------------- RoPE cos/sin table: [2048][32] float2 ----------------
__global__ __launch_bounds__(256) void rope_table_kernel(float2* __restrict__ tab) {
  int idx = blockIdx.x * 256 + threadIdx.x;   // 65536
  int s = idx >> 5, i = idx & 31;
  float fr = powf(10000.0f, -(float)i * (1.0f / 32.0f));
  float ang = (float)s * fr;
  tab[idx] = make_float2(cosf(ang), sinf(ang));
}

// ---------------- GEMM: C[M][N] = A[M][1024] @ W[N][1024]^T  (bf16 in, fp32 acc) ----
// 128x128 tile, BK=32, 4 waves (2x2), global_load_lds staging, XOR-swizzled LDS.
template<int OUTF32>
__global__ __launch_bounds__(256) void gemm_bt(
    const __hip_bfloat16* __restrict__ A, const __hip_bfloat16* __restrict__ W,
    void* __restrict__ C, const int N) {
  __shared__ alignas(16) __hip_bfloat16 As[128 * 32];
  __shared__ alignas(16) __hip_bfloat16 Bs[128 * 32];
  const int t = threadIdx.x;
  const int m0 = blockIdx.x * 128, n0 = blockIdx.y * 128;
  const int w = t >> 6, lane = t & 63, l15 = lane & 15, hi = lane >> 4;
  const int wm = w >> 1, wn = w & 1;
  // staging: 512 chunks of 16B per tile; thread t covers chunk t and t+256
  const int srow = t >> 2, scs = (t & 3) ^ (srow & 3);   // inverse-swizzled source chunk
  const __hip_bfloat16* aSrcA = A + (size_t)(m0 + srow) * DM + scs * 8;
  const __hip_bfloat16* aSrcB = aSrcA + (size_t)64 * DM;
  const __hip_bfloat16* bSrcA = W + (size_t)(n0 + srow) * DM + scs * 8;
  const __hip_bfloat16* bSrcB = bSrcA + (size_t)64 * DM;
  char* aDstA = (char*)As + t * 16; char* aDstB = (char*)As + (t + 256) * 16;
  char* bDstA = (char*)Bs + t * 16; char* bDstB = (char*)Bs + (t + 256) * 16;
  const int r3 = l15 & 3;
  int aoff[4], boff[4];
#pragma unroll
  for (int i = 0; i < 4; ++i) {
    aoff[i] = (wm * 64 + i * 16 + l15) * 64 + ((hi ^ r3) * 16);   // bytes
    boff[i] = (wn * 64 + i * 16 + l15) * 64 + ((hi ^ r3) * 16);
  }
  f32x4 acc[4][4] = {};
  for (int kt = 0; kt < DM; kt += 32) {
    gload_lds16(aSrcA + kt, aDstA);
    gload_lds16(aSrcB + kt, aDstB);
    gload_lds16(bSrcA + kt, bDstA);
    gload_lds16(bSrcB + kt, bDstB);
    __syncthreads();
    short8 af[4], bfr[4];
#pragma unroll
    for (int i = 0; i < 4; ++i) af[i] = *(const short8*)((const char*)As + aoff[i]);
#pragma unroll
    for (int i = 0; i < 4; ++i) bfr[i] = *(const short8*)((const char*)Bs + boff[i]);
#pragma unroll
    for (int mi = 0; mi < 4; ++mi)
#pragma unroll
      for (int ni = 0; ni < 4; ++ni)
        acc[mi][ni] = mfma16(af[mi], bfr[ni], acc[mi][ni]);
    __syncthreads();
  }
  const int mBase = m0 + wm * 64, nBase = n0 + wn * 64;
  if (OUTF32) {
    float* Cf = (float*)C;
#pragma unroll
    for (int mi = 0; mi < 4; ++mi)
#pragma unroll
      for (int ni = 0; ni < 4; ++ni) {
        int m = mBase + mi * 16 + hi * 4, n = nBase + ni * 16 + l15;
#pragma unroll
        for (int r = 0; r < 4; ++r)
          Cf[(size_t)(m + r) * N + n] = acc[mi][ni][r];
      }
  } else {
    unsigned short* Cb = (unsigned short*)C;
#pragma unroll
    for (int mi = 0; mi < 4; ++mi)
#pragma unroll
      for (int ni = 0; ni < 4; ++ni) {
        int m = mBase + mi * 16 + hi * 4, n = nBase + ni * 16 + l15;
#pragma unroll
        for (int r = 0; r < 4; ++r)
          Cb[(size_t)(m + r) * N + n] = f2bf(acc[mi][ni][r]);
      }
  }
}

// ---------------- RoPE: rotate Q (cols 0..1023) and K (cols 1024..2047) in place ----
__global__ __launch_bounds__(256) void rope_kernel(
    __hip_bfloat16* __restrict__ QKV, const float2* __restrict__ tab) {
  int chunk = blockIdx.x * 256 + threadIdx.x;   // 4096 rows * 256 chunks
  int row = chunk >> 8; int c0 = (chunk & 255) << 3;
  int s = row & (SEQ - 1);
  const float2* tb = tab + s * 32 + ((c0 & 63) >> 1);
  __hip_bfloat16* p = QKV + (size_t)row * 3072 + c0;
  union { short8 v; unsigned short e[8]; } u; u.v = *(const short8*)p;
  union { short8 v; unsigned short e[8]; } o;
#pragma unroll
  for (int k = 0; k < 4; ++k) {
    float2 cs = tb[k];
    float x1 = bf2f(u.e[2 * k]), x2 = bf2f(u.e[2 * k + 1]);
    o.e[2 * k]     = f2bf(cs.x * x1 - cs.y * x2);
    o.e[2 * k + 1] = f2bf(cs.y * x1 + cs.x * x2);
  }
  *(short8*)p = o.v;
}

// ---------------- V transpose: Vt[bh][d][s] = V[b][s][h*64+d] ----------------
__global__ __launch_bounds__(256) void transpose_v(
    const __hip_bfloat16* __restrict__ QKV, __hip_bfloat16* __restrict__ Vt) {
  const int st = blockIdx.x, bh = blockIdx.y, b = bh >> 4, h = bh & 15;
  __shared__ alignas(16) __hip_bfloat16 tile[64][80];   // pad 16 -> 160B rows
  const int t = threadIdx.x, s0 = st * 64;
#pragma unroll
  for (int i = 0; i < 2; ++i) {
    int idx = i * 256 + t; int r = idx >> 3, c = idx & 7;
    short8 v = *(const short8*)(QKV + (size_t)(b * SEQ + s0 + r) * 3072 + 2048 + h * 64 + c * 8);
    *(short8*)&tile[r][c * 8] = v;
  }
  __syncthreads();
#pragma unroll
  for (int i = 0; i < 2; ++i) {
    int idx = i * 256 + t; int d = idx >> 3, c = idx & 7;
    union { short8 v; short e[8]; } u;
#pragma unroll
    for (int j = 0; j < 8; ++j) u.e[j] = *(short*)&tile[c * 8 + j][d];
    *(short8*)(Vt + ((size_t)bh * 64 + d) * SEQ + s0 + c * 8) = u.v;
  }
}

// ---------------- Flash attention (causal), swapped QK^T, online softmax ----------
// 4 waves x 16 q rows = 64-q blocks; KV tiles of 64; K,V staged via global_load_lds
// into XOR-swizzled LDS; P^T -> B-operand redistribution via 16 shuffles/tile.
__global__ __launch_bounds__(256) void attn_kernel(
    const __hip_bfloat16* __restrict__ QKV, const __hip_bfloat16* __restrict__ Vt,
    __hip_bfloat16* __restrict__ Ao) {
  const int qt = blockIdx.x, bh = blockIdx.y, b = bh >> 4, h = bh & 15;
  __shared__ alignas(16) __hip_bfloat16 Ks[64 * 64];
  __shared__ alignas(16) __hip_bfloat16 Vs[64 * 64];
  const int t = threadIdx.x, w = t >> 6, lane = t & 63, l15 = lane & 15, hi = lane >> 4;
  const int qrow = qt * 64 + w * 16 + l15;
  const __hip_bfloat16* Qp = QKV + (size_t)(b * SEQ + qrow) * 3072 + h * 64 + hi * 8;
  const short8 qf0 = *(const short8*)Qp;          // B-op frag, d = 0..31
  const short8 qf1 = *(const short8*)(Qp + 32);   // d = 32..63
  const int sr = t >> 3, sc = t & 7, scs = sc ^ (sr & 7);
  const __hip_bfloat16* kSrcA = QKV + (size_t)(b * SEQ + sr) * 3072 + DM + h * 64 + scs * 8;
  const __hip_bfloat16* kSrcB = kSrcA + (size_t)32 * 3072;
  const __hip_bfloat16* vSrcA = Vt + ((size_t)bh * 64 + sr) * SEQ + scs * 8;
  const __hip_bfloat16* vSrcB = vSrcA + (size_t)32 * SEQ;
  char* kDstA = (char*)Ks + t * 16;  char* kDstB = (char*)Ks + (t + 256) * 16;
  char* vDstA = (char*)Vs + t * 16;  char* vDstB = (char*)Vs + (t + 256) * 16;
  const int r7 = l15 & 7;
  f32x4 ot[4] = {};
  float m_run = -INFINITY, l_run = 0.0f;
  for (int kvt = 0; kvt <= qt; ++kvt) {
    gload_lds16(kSrcA + (size_t)(kvt * 64) * 3072, kDstA);
    gload_lds16(kSrcB + (size_t)(kvt * 64) * 3072, kDstB);
    gload_lds16(vSrcA + kvt * 64, vDstA);
    gload_lds16(vSrcB + kvt * 64, vDstB);
    __syncthreads();
    const bool diag = (kvt == qt);
    const int mcmax = diag ? w : 3;
    float p[4][4];
#pragma unroll
    for (int mc = 0; mc < 4; ++mc) {
      f32x4 st = {};
      if (mc <= mcmax) {
        const char* rb = (const char*)Ks + (mc * 16 + l15) * 128;
        short8 a0 = *(const short8*)(rb + ((hi ^ r7) * 16));
        short8 a1 = *(const short8*)(rb + (((4 + hi) ^ r7) * 16));
        st = mfma16(a0, qf0, st);   // S^T[kv][q], d = 0..31
        st = mfma16(a1, qf1, st);   // d = 32..63
      }
#pragma unroll
      for (int r = 0; r < 4; ++r) {
        bool valid = (mc <= mcmax) && (!diag || (mc * 16 + hi * 4 + r) <= (w * 16 + l15));
        p[mc][r] = valid ? st[r] * 0.125f : -INFINITY;
      }
    }
    float mt = -INFINITY;
#pragma unroll
    for (int mc = 0; mc < 4; ++mc)
#pragma unroll
      for (int r = 0; r < 4; ++r) mt = fmaxf(mt, p[mc][r]);
    mt = fmaxf(mt, __shfl_xor(mt, 16, 64));
    mt = fmaxf(mt, __shfl_xor(mt, 32, 64));
    const float m_new = fmaxf(m_run, mt);
    const float alpha = __expf(m_run - m_new);
    float ls = 0.0f;
#pragma unroll
    for (int mc = 0; mc < 4; ++mc)
#pragma unroll
      for (int r = 0; r < 4; ++r) { float e = __expf(p[mc][r] - m_new); p[mc][r] = e; ls += e; }
    ls += __shfl_xor(ls, 16, 64);
    ls += __shfl_xor(ls, 32, 64);
    l_run = l_run * alpha + ls;
    m_run = m_new;
#pragma unroll
    for (int d = 0; d < 4; ++d) ot[d] *= alpha;
    // pack P rows to bf16 pairs, redistribute to PV B-operand layout
    unsigned pu[4][2];
#pragma unroll
    for (int mc = 0; mc < 4; ++mc) {
      pu[mc][0] = ((unsigned)f2bf(p[mc][1]) << 16) | f2bf(p[mc][0]);
      pu[mc][1] = ((unsigned)f2bf(p[mc][3]) << 16) | f2bf(p[mc][2]);
    }
    const int srcA = ((hi & 1) << 5) + l15;   // lane holding kv 8hi+0..3 of needed frag
    const int srcB = srcA + 16;               // kv 8hi+4..7
#pragma unroll
    for (int ks = 0; ks < 2; ++ks) {
      unsigned a0 = (unsigned)__shfl((int)pu[2 * ks][0], srcA, 64);
      unsigned a1 = (unsigned)__shfl((int)pu[2 * ks][1], srcA, 64);
      unsigned a2 = (unsigned)__shfl((int)pu[2 * ks][0], srcB, 64);
      unsigned a3 = (unsigned)__shfl((int)pu[2 * ks][1], srcB, 64);
      unsigned b0 = (unsigned)__shfl((int)pu[2 * ks + 1][0], srcA, 64);
      unsigned b1 = (unsigned)__shfl((int)pu[2 * ks + 1][1], srcA, 64);
      unsigned b2 = (unsigned)__shfl((int)pu[2 * ks + 1][0], srcB, 64);
      unsigned b3 = (unsigned)__shfl((int)pu[2 * ks + 1][1], srcB, 64);
      union { unsigned u[4]; short8 v; } pf;
      pf.u[0] = (hi < 2) ? a0 : b0;
      pf.u[1] = (hi < 2) ? a1 : b1;
      pf.u[2] = (hi < 2) ? a2 : b2;
      pf.u[3] = (hi < 2) ? a3 : b3;
#pragma unroll
      for (int d = 0; d < 4; ++d) {
        const char* rb = (const char*)Vs + (d * 16 + l15) * 128;
        short8 av = *(const short8*)(rb + (((ks * 4 + hi) ^ r7) * 16));
        ot[d] = mfma16(av, pf.v, ot[d]);    // O^T[d][q]
      }
    }
    __syncthreads();
  }
  const float inv = 1.0f / l_run;
  __hip_bfloat16* Op = Ao + (size_t)(b * SEQ + qrow) * DM + h * 64;
#pragma unroll
  for (int d = 0; d < 4; ++d) {
    union { short4v v; unsigned short e[4]; } ou;
#pragma unroll
    for (int r = 0; r < 4; ++r) ou.e[r] = f2bf(ot[d][r] * inv);
    *(short4v*)(Op + d * 16 + hi * 4) = ou.v;
  }
}

// ---------------- launch ----------------
extern "C" void kernel_launch(void* const* d_in, const int* in_sizes, int n_in,
                              void* d_out, int out_size, void* d_ws, size_t ws_size,
                              hipStream_t stream) {
  const float* x  = (const float*)d_in[0];
  const float* Wq = (const float*)d_in[1];
  const float* Wk = (const float*)d_in[2];
  const float* Wv = (const float*)d_in[3];
  const float* Wo = (const float*)d_in[4];
  char* ws = (char*)d_ws;
  // ws layout (bytes): [0,8M) xb then reused as attn-out; [8M,16M) Wb (q,k,v,o);
  // [16M,40M) QKV bf16 [4096][3072]; [40M,48M) Vt; [48M,48.5M) rope table
  __hip_bfloat16* xb   = (__hip_bfloat16*)ws;
  __hip_bfloat16* Ao   = (__hip_bfloat16*)ws;                  // aliases xb (dead by then)
  __hip_bfloat16* Wb   = (__hip_bfloat16*)(ws + 8388608);
  __hip_bfloat16* QKVb = (__hip_bfloat16*)(ws + 16777216);
  __hip_bfloat16* Vt   = (__hip_bfloat16*)(ws + 41943040);
  float2*         tab  = (float2*)(ws + 50331648);
  prep_kernel<<<4096, 256, 0, stream>>>(x, Wq, Wk, Wv, Wo, xb, Wb);
  rope_table_kernel<<<256, 256, 0, stream>>>(tab);
  gemm_bt<0><<<dim3(32, 24), 256, 0, stream>>>(xb, Wb, QKVb, 3072);
  rope_kernel<<<4096, 256, 0, stream>>>(QKVb, tab);
  transpose_v<<<dim3(32, 32), 256, 0, stream>>>(QKVb, Vt);
  attn_kernel<<<dim3(32, 32), 256, 0, stream>>>(QKVb, Vt, Ao);
  gemm_bt<1><<<dim3(32, 8), 256, 0, stream>>>(Ao, Wb + 3 * 1048576, d_out, 1024);
}

// Round 2
// 206.969 us; speedup vs baseline: 1.1754x; 1.1754x over previous
//
#include <hip/hip_runtime.h>
#include <hip/hip_bf16.h>
#include <stdint.h>
#include <math.h>

#define SEQ 2048
#define DM 1024
#define NH 16
#define DK 64

typedef __attribute__((ext_vector_type(8))) short short8;
typedef __attribute__((ext_vector_type(4))) short short4v;
typedef __attribute__((ext_vector_type(4))) float f32x4;

__device__ __forceinline__ float bf2f(unsigned short s) {
  unsigned u = ((unsigned)s) << 16; float f; __builtin_memcpy(&f, &u, 4); return f;
}
__device__ __forceinline__ unsigned short f2bf(float f) {
  unsigned u; __builtin_memcpy(&u, &f, 4);
  u += 0x7FFFu + ((u >> 16) & 1u);          // RNE
  return (unsigned short)(u >> 16);
}
__device__ __forceinline__ f32x4 mfma16(short8 a, short8 b, f32x4 c) {
  return __builtin_amdgcn_mfma_f32_16x16x32_bf16(a, b, c, 0, 0, 0);
}
__device__ __forceinline__ void gload_lds16(const void* g, void* l) {
  __builtin_amdgcn_global_load_lds((const __attribute__((address_space(1))) void*)g,
                                   (__attribute__((address_space(3))) void*)l, 16, 0, 0);
}

// ---------------- prep: fp32 -> bf16 for x and the 4 weight matrices ----------------
__global__ __launch_bounds__(256) void prep_kernel(
    const float* __restrict__ x, const float* __restrict__ Wq,
    const float* __restrict__ Wk, const float* __restrict__ Wv,
    const float* __restrict__ Wo, __hip_bfloat16* __restrict__ xb,
    __hip_bfloat16* __restrict__ Wb) {
  int chunk = blockIdx.x * 256 + threadIdx.x;   // 1,048,576 chunks of 8 elems
  const float* src; __hip_bfloat16* dst;
  if (chunk < 524288) { src = x + (size_t)chunk * 8; dst = xb + (size_t)chunk * 8; }
  else {
    int wc = chunk - 524288; int wi = wc >> 17; int wo_ = wc & 131071;
    const float* Ws = (wi == 0) ? Wq : (wi == 1) ? Wk : (wi == 2) ? Wv : Wo;
    src = Ws + (size_t)wo_ * 8; dst = Wb + (size_t)wi * 1048576 + (size_t)wo_ * 8;
  }
  float4 a = *(const float4*)src; float4 b = *(const float4*)(src + 4);
  union { short8 v; unsigned short e[8]; } u;
  u.e[0] = f2bf(a.x); u.e[1] = f2bf(a.y); u.e[2] = f2bf(a.z); u.e[3] = f2bf(a.w);
  u.e[4] = f2bf(b.x); u.e[5] = f2bf(b.y); u.e[6] = f2bf(b.z); u.e[7] = f2bf(b.w);
  *(short8*)dst = u.v;
}

// ---------------- RoPE cos/sin table: [2048][32] float2 ----------------
__global__ __launch_bounds__(256) void rope_table_kernel(float2* __restrict__ tab) {
  int idx = blockIdx.x * 256 + threadIdx.x;   // 65536
  int s = idx >> 5, i = idx & 31;
  float fr = powf(10000.0f, -(float)i * (1.0f / 32.0f));
  float ang = (float)s * fr;
  tab[idx] = make_float2(cosf(ang), sinf(ang));
}

// ---------------- GEMM: C[M][N] = A[M][1024] @ W[N][1024]^T  (bf16 in, fp32 acc) ----
// 128x128 tile, BK=32, 4 waves (2x2), global_load_lds staging, XOR-swizzled LDS.
template<int OUTF32>
__global__ __launch_bounds__(256) void gemm_bt(
    const __hip_bfloat16* __restrict__ A, const __hip_bfloat16* __restrict__ W,
    void* __restrict__ C, const int N) {
  __shared__ alignas(16) __hip_bfloat16 As[128 * 32];
  __shared__ alignas(16) __hip_bfloat16 Bs[128 * 32];
  const int t = threadIdx.x;
  const int m0 = blockIdx.x * 128, n0 = blockIdx.y * 128;
  const int w = t >> 6, lane = t & 63, l15 = lane & 15, hi = lane >> 4;
  const int wm = w >> 1, wn = w & 1;
  // staging: 512 chunks of 16B per tile; thread t covers chunk t and t+256
  const int srow = t >> 2, scs = (t & 3) ^ (srow & 3);   // inverse-swizzled source chunk
  const __hip_bfloat16* aSrcA = A + (size_t)(m0 + srow) * DM + scs * 8;
  const __hip_bfloat16* aSrcB = aSrcA + (size_t)64 * DM;
  const __hip_bfloat16* bSrcA = W + (size_t)(n0 + srow) * DM + scs * 8;
  const __hip_bfloat16* bSrcB = bSrcA + (size_t)64 * DM;
  char* aDstA = (char*)As + t * 16; char* aDstB = (char*)As + (t + 256) * 16;
  char* bDstA = (char*)Bs + t * 16; char* bDstB = (char*)Bs + (t + 256) * 16;
  const int r3 = l15 & 3;
  int aoff[4], boff[4];
#pragma unroll
  for (int i = 0; i < 4; ++i) {
    aoff[i] = (wm * 64 + i * 16 + l15) * 64 + ((hi ^ r3) * 16);   // bytes
    boff[i] = (wn * 64 + i * 16 + l15) * 64 + ((hi ^ r3) * 16);
  }
  f32x4 acc[4][4] = {};
  for (int kt = 0; kt < DM; kt += 32) {
    gload_lds16(aSrcA + kt, aDstA);
    gload_lds16(aSrcB + kt, aDstB);
    gload_lds16(bSrcA + kt, bDstA);
    gload_lds16(bSrcB + kt, bDstB);
    __syncthreads();
    short8 af[4], bfr[4];
#pragma unroll
    for (int i = 0; i < 4; ++i) af[i] = *(const short8*)((const char*)As + aoff[i]);
#pragma unroll
    for (int i = 0; i < 4; ++i) bfr[i] = *(const short8*)((const char*)Bs + boff[i]);
#pragma unroll
    for (int mi = 0; mi < 4; ++mi)
#pragma unroll
      for (int ni = 0; ni < 4; ++ni)
        acc[mi][ni] = mfma16(af[mi], bfr[ni], acc[mi][ni]);
    __syncthreads();
  }
  const int mBase = m0 + wm * 64, nBase = n0 + wn * 64;
  if (OUTF32) {
    float* Cf = (float*)C;
#pragma unroll
    for (int mi = 0; mi < 4; ++mi)
#pragma unroll
      for (int ni = 0; ni < 4; ++ni) {
        int m = mBase + mi * 16 + hi * 4, n = nBase + ni * 16 + l15;
#pragma unroll
        for (int r = 0; r < 4; ++r)
          Cf[(size_t)(m + r) * N + n] = acc[mi][ni][r];
      }
  } else {
    unsigned short* Cb = (unsigned short*)C;
#pragma unroll
    for (int mi = 0; mi < 4; ++mi)
#pragma unroll
      for (int ni = 0; ni < 4; ++ni) {
        int m = mBase + mi * 16 + hi * 4, n = nBase + ni * 16 + l15;
#pragma unroll
        for (int r = 0; r < 4; ++r)
          Cb[(size_t)(m + r) * N + n] = f2bf(acc[mi][ni][r]);
      }
  }
}

// ---------------- RoPE: rotate Q (cols 0..1023) and K (cols 1024..2047) in place ----
__global__ __launch_bounds__(256) void rope_kernel(
    __hip_bfloat16* __restrict__ QKV, const float2* __restrict__ tab) {
  int chunk = blockIdx.x * 256 + threadIdx.x;   // 4096 rows * 256 chunks
  int row = chunk >> 8; int c0 = (chunk & 255) << 3;
  int s = row & (SEQ - 1);
  const float2* tb = tab + s * 32 + ((c0 & 63) >> 1);
  __hip_bfloat16* p = QKV + (size_t)row * 3072 + c0;
  union { short8 v; unsigned short e[8]; } u; u.v = *(const short8*)p;
  union { short8 v; unsigned short e[8]; } o;
#pragma unroll
  for (int k = 0; k < 4; ++k) {
    float2 cs = tb[k];
    float x1 = bf2f(u.e[2 * k]), x2 = bf2f(u.e[2 * k + 1]);
    o.e[2 * k]     = f2bf(cs.x * x1 - cs.y * x2);
    o.e[2 * k + 1] = f2bf(cs.y * x1 + cs.x * x2);
  }
  *(short8*)p = o.v;
}

// ---------------- V transpose: Vt[bh][d][s] = V[b][s][h*64+d] ----------------
__global__ __launch_bounds__(256) void transpose_v(
    const __hip_bfloat16* __restrict__ QKV, __hip_bfloat16* __restrict__ Vt) {
  const int st = blockIdx.x, bh = blockIdx.y, b = bh >> 4, h = bh & 15;
  __shared__ alignas(16) __hip_bfloat16 tile[64][80];   // pad 16 -> 160B rows
  const int t = threadIdx.x, s0 = st * 64;
#pragma unroll
  for (int i = 0; i < 2; ++i) {
    int idx = i * 256 + t; int r = idx >> 3, c = idx & 7;
    short8 v = *(const short8*)(QKV + (size_t)(b * SEQ + s0 + r) * 3072 + 2048 + h * 64 + c * 8);
    *(short8*)&tile[r][c * 8] = v;
  }
  __syncthreads();
#pragma unroll
  for (int i = 0; i < 2; ++i) {
    int idx = i * 256 + t; int d = idx >> 3, c = idx & 7;
    union { short8 v; short e[8]; } u;
#pragma unroll
    for (int j = 0; j < 8; ++j) u.e[j] = *(short*)&tile[c * 8 + j][d];
    *(short8*)(Vt + ((size_t)bh * 64 + d) * SEQ + s0 + c * 8) = u.v;
  }
}

// ---------------- Flash attention (causal), swapped QK^T, online softmax ----------
// R2: 2-phase double-buffered K/V staging (issue next tile's global_load_lds BEFORE
// computing current; ONE barrier per tile) + 1D grid with XCD-locality (same head
// pinned to one XCD's L2) and heavy-first dispatch (qt descending).
__global__ __launch_bounds__(256) void attn_kernel(
    const __hip_bfloat16* __restrict__ QKV, const __hip_bfloat16* __restrict__ Vt,
    __hip_bfloat16* __restrict__ Ao) {
  const int id = blockIdx.x;
  const int bh = (id & 7) * 4 + ((id >> 3) & 3);   // id%8 constant per bh -> same XCD
  const int qt = 31 - (id >> 5);                   // heavy blocks dispatch first
  const int b = bh >> 4, h = bh & 15;
  __shared__ alignas(16) __hip_bfloat16 Ks[2][64 * 64];
  __shared__ alignas(16) __hip_bfloat16 Vs[2][64 * 64];
  const int t = threadIdx.x, w = t >> 6, lane = t & 63, l15 = lane & 15, hi = lane >> 4;
  const int qrow = qt * 64 + w * 16 + l15;
  const __hip_bfloat16* Qp = QKV + (size_t)(b * SEQ + qrow) * 3072 + h * 64 + hi * 8;
  const short8 qf0 = *(const short8*)Qp;          // B-op frag, d = 0..31
  const short8 qf1 = *(const short8*)(Qp + 32);   // d = 32..63
  const int sr = t >> 3, sc = t & 7, scs = sc ^ (sr & 7);
  const __hip_bfloat16* kSrcA = QKV + (size_t)(b * SEQ + sr) * 3072 + DM + h * 64 + scs * 8;
  const __hip_bfloat16* kSrcB = kSrcA + (size_t)32 * 3072;
  const __hip_bfloat16* vSrcA = Vt + ((size_t)bh * 64 + sr) * SEQ + scs * 8;
  const __hip_bfloat16* vSrcB = vSrcA + (size_t)32 * SEQ;
  char* kDstA = (char*)Ks + t * 16;  char* kDstB = (char*)Ks + (t + 256) * 16;
  char* vDstA = (char*)Vs + t * 16;  char* vDstB = (char*)Vs + (t + 256) * 16;
  const int r7 = l15 & 7;
  f32x4 ot[4] = {};
  float m_run = -INFINITY, l_run = 0.0f;

  // prologue: stage tile 0 into buffer 0
  {
    gload_lds16(kSrcA, kDstA);
    gload_lds16(kSrcB, kDstB);
    gload_lds16(vSrcA, vDstA);
    gload_lds16(vSrcB, vDstB);
  }
  __syncthreads();

  for (int kvt = 0; kvt <= qt; ++kvt) {
    const int cur = kvt & 1;
    // prefetch next tile into the other buffer; latency hides under compute
    if (kvt < qt) {
      const size_t ko = (size_t)((kvt + 1) * 64) * 3072;
      const int vo = (kvt + 1) * 64;
      gload_lds16(kSrcA + ko, kDstA + (cur ^ 1) * 8192);
      gload_lds16(kSrcB + ko, kDstB + (cur ^ 1) * 8192);
      gload_lds16(vSrcA + vo, vDstA + (cur ^ 1) * 8192);
      gload_lds16(vSrcB + vo, vDstB + (cur ^ 1) * 8192);
    }
    const char* Kbase = (const char*)Ks + cur * 8192;
    const char* Vbase = (const char*)Vs + cur * 8192;
    const bool diag = (kvt == qt);
    const int mcmax = diag ? w : 3;
    float p[4][4];
#pragma unroll
    for (int mc = 0; mc < 4; ++mc) {
      f32x4 st = {};
      if (mc <= mcmax) {
        const char* rb = Kbase + (mc * 16 + l15) * 128;
        short8 a0 = *(const short8*)(rb + ((hi ^ r7) * 16));
        short8 a1 = *(const short8*)(rb + (((4 + hi) ^ r7) * 16));
        st = mfma16(a0, qf0, st);   // S^T[kv][q], d = 0..31
        st = mfma16(a1, qf1, st);   // d = 32..63
      }
#pragma unroll
      for (int r = 0; r < 4; ++r) {
        bool valid = (mc <= mcmax) && (!diag || (mc * 16 + hi * 4 + r) <= (w * 16 + l15));
        p[mc][r] = valid ? st[r] * 0.125f : -INFINITY;
      }
    }
    float mt = -INFINITY;
#pragma unroll
    for (int mc = 0; mc < 4; ++mc)
#pragma unroll
      for (int r = 0; r < 4; ++r) mt = fmaxf(mt, p[mc][r]);
    mt = fmaxf(mt, __shfl_xor(mt, 16, 64));
    mt = fmaxf(mt, __shfl_xor(mt, 32, 64));
    const float m_new = fmaxf(m_run, mt);
    const float alpha = __expf(m_run - m_new);
    float ls = 0.0f;
#pragma unroll
    for (int mc = 0; mc < 4; ++mc)
#pragma unroll
      for (int r = 0; r < 4; ++r) { float e = __expf(p[mc][r] - m_new); p[mc][r] = e; ls += e; }
    ls += __shfl_xor(ls, 16, 64);
    ls += __shfl_xor(ls, 32, 64);
    l_run = l_run * alpha + ls;
    m_run = m_new;
#pragma unroll
    for (int d = 0; d < 4; ++d) ot[d] *= alpha;
    // pack P rows to bf16 pairs, redistribute to PV B-operand layout
    unsigned pu[4][2];
#pragma unroll
    for (int mc = 0; mc < 4; ++mc) {
      pu[mc][0] = ((unsigned)f2bf(p[mc][1]) << 16) | f2bf(p[mc][0]);
      pu[mc][1] = ((unsigned)f2bf(p[mc][3]) << 16) | f2bf(p[mc][2]);
    }
    const int srcA = ((hi & 1) << 5) + l15;   // lane holding kv 8hi+0..3 of needed frag
    const int srcB = srcA + 16;               // kv 8hi+4..7
#pragma unroll
    for (int ks = 0; ks < 2; ++ks) {
      unsigned a0 = (unsigned)__shfl((int)pu[2 * ks][0], srcA, 64);
      unsigned a1 = (unsigned)__shfl((int)pu[2 * ks][1], srcA, 64);
      unsigned a2 = (unsigned)__shfl((int)pu[2 * ks][0], srcB, 64);
      unsigned a3 = (unsigned)__shfl((int)pu[2 * ks][1], srcB, 64);
      unsigned b0 = (unsigned)__shfl((int)pu[2 * ks + 1][0], srcA, 64);
      unsigned b1 = (unsigned)__shfl((int)pu[2 * ks + 1][1], srcA, 64);
      unsigned b2 = (unsigned)__shfl((int)pu[2 * ks + 1][0], srcB, 64);
      unsigned b3 = (unsigned)__shfl((int)pu[2 * ks + 1][1], srcB, 64);
      union { unsigned u[4]; short8 v; } pf;
      pf.u[0] = (hi < 2) ? a0 : b0;
      pf.u[1] = (hi < 2) ? a1 : b1;
      pf.u[2] = (hi < 2) ? a2 : b2;
      pf.u[3] = (hi < 2) ? a3 : b3;
#pragma unroll
      for (int d = 0; d < 4; ++d) {
        const char* rb = Vbase + (d * 16 + l15) * 128;
        short8 av = *(const short8*)(rb + (((ks * 4 + hi) ^ r7) * 16));
        ot[d] = mfma16(av, pf.v, ot[d]);    // O^T[d][q]
      }
    }
    __syncthreads();   // next buffer staged + all reads of cur done
  }
  const float inv = 1.0f / l_run;
  __hip_bfloat16* Op = Ao + (size_t)(b * SEQ + qrow) * DM + h * 64;
#pragma unroll
  for (int d = 0; d < 4; ++d) {
    union { short4v v; unsigned short e[4]; } ou;
#pragma unroll
    for (int r = 0; r < 4; ++r) ou.e[r] = f2bf(ot[d][r] * inv);
    *(short4v*)(Op + d * 16 + hi * 4) = ou.v;
  }
}

// ---------------- launch ----------------
extern "C" void kernel_launch(void* const* d_in, const int* in_sizes, int n_in,
                              void* d_out, int out_size, void* d_ws, size_t ws_size,
                              hipStream_t stream) {
  const float* x  = (const float*)d_in[0];
  const float* Wq = (const float*)d_in[1];
  const float* Wk = (const float*)d_in[2];
  const float* Wv = (const float*)d_in[3];
  const float* Wo = (const float*)d_in[4];
  char* ws = (char*)d_ws;
  // ws layout (bytes): [0,8M) xb then reused as attn-out; [8M,16M) Wb (q,k,v,o);
  // [16M,40M) QKV bf16 [4096][3072]; [40M,48M) Vt; [48M,48.5M) rope table
  __hip_bfloat16* xb   = (__hip_bfloat16*)ws;
  __hip_bfloat16* Ao   = (__hip_bfloat16*)ws;                  // aliases xb (dead by then)
  __hip_bfloat16* Wb   = (__hip_bfloat16*)(ws + 8388608);
  __hip_bfloat16* QKVb = (__hip_bfloat16*)(ws + 16777216);
  __hip_bfloat16* Vt   = (__hip_bfloat16*)(ws + 41943040);
  float2*         tab  = (float2*)(ws + 50331648);
  prep_kernel<<<4096, 256, 0, stream>>>(x, Wq, Wk, Wv, Wo, xb, Wb);
  rope_table_kernel<<<256, 256, 0, stream>>>(tab);
  gemm_bt<0><<<dim3(32, 24), 256, 0, stream>>>(xb, Wb, QKVb, 3072);
  rope_kernel<<<4096, 256, 0, stream>>>(QKVb, tab);
  transpose_v<<<dim3(32, 32), 256, 0, stream>>>(QKVb, Vt);
  attn_kernel<<<1024, 256, 0, stream>>>(QKVb, Vt, Ao);
  gemm_bt<1><<<dim3(32, 8), 256, 0, stream>>>(Ao, Wb + 3 * 1048576, d_out, 1024);
}